// Round 4
// baseline (989.306 us; speedup 1.0000x reference)
//
#include <hip/hip_runtime.h>
#include <hip/hip_bf16.h>
#include <stdint.h>

#define IN_F 1024
#define OUT_F 1024
#define NG 8
#define KSPLINE 8192            // IN_F * NG
#define KDIM 9216               // KSPLINE + IN_F
#define KHALF 4608              // split-K half (72 tiles of 64)
#define M_ROWS 8192
#define LOG2E 1.4426950408889634f
// KC = 1.75 * sqrt(log2(e)) : basis = exp(-((xn-c)*1.75)^2) = 2^(-(xn*KC - c*KC)^2)
#define KC 2.1019642153762872f

#define A_BLOCKS (M_ROWS / 4)           // 2048 (4 rows per block, wave-per-row)
#define W_BLOCKS ((OUT_F * 2304) / 256) // 9216
#define RB (KDIM * 2)                   // A/W row bytes (18432)

using half4v = __attribute__((ext_vector_type(4))) _Float16;
using half8  = __attribute__((ext_vector_type(8))) _Float16;
using f32x4  = __attribute__((ext_vector_type(4))) float;

#define AS1 __attribute__((address_space(1)))
#define AS3 __attribute__((address_space(3)))

// ---- merged prep: blocks [0, A_BLOCKS) build A; [A_BLOCKS, +W_BLOCKS) build W
__global__ __launch_bounds__(256) void prep_kernel(
        const float* __restrict__ x, const float* __restrict__ gamma,
        const float* __restrict__ beta, const float* __restrict__ sw,
        const float* __restrict__ bw, _Float16* __restrict__ A,
        _Float16* __restrict__ W) {
    if (blockIdx.x >= A_BLOCKS) {
        int idx = (blockIdx.x - A_BLOCKS) * 256 + threadIdx.x;  // one float4 each
        int o   = idx / 2304;
        int k4  = idx - o * 2304;
        float4 v;
        if (k4 < 2048) v = ((const float4*)sw)[(size_t)o * 2048 + k4];
        else           v = ((const float4*)bw)[(size_t)o * 256 + (k4 - 2048)];
        half4v h = { (_Float16)v.x, (_Float16)v.y, (_Float16)v.z, (_Float16)v.w };
        *(half4v*)(W + (size_t)idx * 4) = h;
        return;
    }
    const int wave = threadIdx.x >> 6, lane = threadIdx.x & 63;
    const int row = blockIdx.x * 4 + wave;
    const float* xr = x + (size_t)row * IN_F;

    float xv[16];
    float s = 0.0f, s2 = 0.0f;
#pragma unroll
    for (int j = 0; j < 16; ++j) {
        float v = xr[j * 64 + lane];
        xv[j] = v;
        s += v;
        s2 += v * v;
    }
#pragma unroll
    for (int off = 32; off > 0; off >>= 1) {
        s  += __shfl_xor(s, off);
        s2 += __shfl_xor(s2, off);
    }
    float mu   = s * (1.0f / IN_F);
    float var  = s2 * (1.0f / IN_F) - mu * mu;
    float rstd = rsqrtf(var + 1e-5f);

    const float cq[8] = {
        -2.0000000f * KC, -1.4285715f * KC, -0.8571429f * KC, -0.2857143f * KC,
         0.2857143f * KC,  0.8571429f * KC,  1.4285715f * KC,  2.0000000f * KC };

    _Float16* Arow = A + (size_t)row * KDIM;
    half8* basis_out = (half8*)Arow;                       // chunk f = feature f
    _Float16* silu_out = Arow + KSPLINE;
#pragma unroll
    for (int j = 0; j < 16; ++j) {
        int f = j * 64 + lane;
        float xs = xv[j];
        float xq = ((xs - mu) * rstd * gamma[f] + beta[f]) * KC;
        half8 h;
#pragma unroll
        for (int g = 0; g < 8; ++g) {
            float v = xq - cq[g];
            h[g] = (_Float16)exp2f(-(v * v));
        }
        basis_out[f] = h;
        silu_out[f] = (_Float16)(xs / (1.0f + exp2f(-xs * LOG2E)));
    }
}

// ---------------- GEMM: 256x256 tile, 8 waves (2Mx4N, per-wave 128x64), BK=64,
// double-buffered 128KB LDS, split-K=2. Software-pipelined 4-phase schedule:
// phase p issues the ds_reads consumed at phase p+1 (4/8/4/8 per phase), so
// every read's slot was proven resident by the PREVIOUS phase's vmcnt(2) +
// barrier. Stages: ph0:A0A1(t+1) ph1:B0B1 ph2:B2B3 ph3:A2A3; vmcnt(2) per
// phase (never 0 mid-loop) proves exactly the slot the next phase reads.
// XOR swizzle (row&7)<<4 both-sides; raw s_barrier; setprio around MFMA.
__global__ __launch_bounds__(512, 2) void gemm_kernel(
        const _Float16* __restrict__ A, const _Float16* __restrict__ W,
        const float* __restrict__ bias, float* __restrict__ C,
        float* __restrict__ P, int ntiles, int gpz) {
    extern __shared__ __align__(16) char smem[];   // 2 x [A 32K | B 32K]
    const int tid  = threadIdx.x;
    const int wave = tid >> 6, lane = tid & 63;
    const int wm = wave >> 2, wn = wave & 3;       // 2M x 4N wave grid

    // bijective XCD swizzle (grid % 8 == 0): 4 bn-siblings per group
    const int lb = blockIdx.x;
    const int per_xcd = gridDim.x >> 5;
    const int xcd = lb & 7, sl = lb >> 3;
    const int g  = xcd * per_xcd + (sl >> 2);
    const int bn = sl & 3;
    const int bm = g / gpz;
    const int z  = g - bm * gpz;

    // ---- staging sources: slot s covers 64 rows (8 per wave), lane chunk
    // pre-swizzled so linear LDS dest yields swizzled layout
    const int l8 = lane >> 3;
    const int chunkswz = ((lane & 7) ^ l8) << 4;
    const size_t zoff = (size_t)z * (KHALF * 2);
    // A slot->rowbase {0,128,64,192}: slots {0,1}=mh0 rows, {2,3}=mh1 rows
    // B slot->rowbase {0,128,32,160}: slots {0,1}=nh0 rows, {2,3}=nh1 rows
    const int gA[4] = {0, 128, 64, 192};
    const int gB[4] = {0, 128, 32, 160};
    const char* pA[4];
    const char* pB[4];
#pragma unroll
    for (int s = 0; s < 4; ++s) {
        pA[s] = (const char*)A + (size_t)(bm * 256 + gA[s] + wave * 8 + l8) * RB
                + zoff + chunkswz;
        pB[s] = (const char*)W + (size_t)(bn * 256 + gB[s] + (wave >> 2) * 64
                + (wave & 3) * 8 + l8) * RB + zoff + chunkswz;
    }

#define STAGE_A(s, nb, colb) __builtin_amdgcn_global_load_lds( \
        (const AS1 void*)(pA[s] + (colb)), \
        (AS3 void*)(smem + (nb) + (s) * 8192 + wave * 1024), 16, 0, 0)
#define STAGE_B(s, nb, colb) __builtin_amdgcn_global_load_lds( \
        (const AS1 void*)(pB[s] + (colb)), \
        (AS3 void*)(smem + (nb) + 32768 + (s) * 8192 + wave * 1024), 16, 0, 0)

    // ---- ds_read offsets (swizzled) ----
    const int lm  = lane & 15;
    const int hi  = (lane >> 4) << 4;
    const int swz = (lm & 7) << 4;
    const int ck0 = (0  + hi) ^ swz;               // kh0 chunk byte
    const int ck1 = (64 + hi) ^ swz;               // kh1
    const int aB0 = (0 + wm) * 8192 + lm * 128;    // Am0 slots; frag mf -> +mf*2048
    const int aB1 = (2 + wm) * 8192 + lm * 128;    // Am1 slots
    const int bB0 = 32768 + (0 + (wn >> 1)) * 8192 + ((wn & 1) * 32 + lm) * 128;
    const int bB1 = 32768 + (2 + (wn >> 1)) * 8192 + ((wn & 1) * 32 + lm) * 128;

    f32x4 acc[8][4] = {};
    half8 aE[4][2], bE[2][2], aO[4][2], bO[2][2];

#define MFMA8(mb, Aa, Bb, nb2)                                                  \
    {                                                                           \
        _Pragma("unroll")                                                       \
        for (int n = 0; n < 2; ++n)                                             \
            _Pragma("unroll")                                                   \
            for (int m = 0; m < 4; ++m)                                         \
                acc[(mb)+m][(nb2)+n] = __builtin_amdgcn_mfma_f32_16x16x32_f16(  \
                    Aa[m][0], Bb[n][0], acc[(mb)+m][(nb2)+n], 0, 0, 0);         \
        _Pragma("unroll")                                                       \
        for (int n = 0; n < 2; ++n)                                             \
            _Pragma("unroll")                                                   \
            for (int m = 0; m < 4; ++m)                                         \
                acc[(mb)+m][(nb2)+n] = __builtin_amdgcn_mfma_f32_16x16x32_f16(  \
                    Aa[m][1], Bb[n][1], acc[(mb)+m][(nb2)+n], 0, 0, 0);         \
    }

#define BAR_MFMA(mb, Aa, Bb, nb2)                                               \
    __builtin_amdgcn_s_barrier();                                               \
    asm volatile("s_waitcnt lgkmcnt(0)" ::: "memory");                          \
    __builtin_amdgcn_sched_barrier(0);                                          \
    __builtin_amdgcn_s_setprio(1);                                              \
    MFMA8(mb, Aa, Bb, nb2)                                                      \
    __builtin_amdgcn_s_setprio(0);                                              \
    __builtin_amdgcn_s_barrier();

#define TILE(cb, nb, AC, BC, AN, BN, colb, pref)                                \
    { /* ---- ph0: MFMA Am0 x Bn01; read Bn23(t); stage A0A1(t+1) ---- */       \
        half8 b1[2][2];                                                         \
        _Pragma("unroll")                                                       \
        for (int n = 0; n < 2; ++n) {                                           \
            b1[n][0] = *(const half8*)(smem + (cb) + bB1 + n * 2048 + ck0);     \
            b1[n][1] = *(const half8*)(smem + (cb) + bB1 + n * 2048 + ck1);     \
        }                                                                       \
        if (pref) { STAGE_A(0, nb, colb); STAGE_A(1, nb, colb);                 \
            asm volatile("s_waitcnt vmcnt(2)" ::: "memory"); }                  \
        else asm volatile("s_waitcnt vmcnt(0)" ::: "memory");                   \
        BAR_MFMA(0, AC, BC, 0)                                                  \
        /* ---- ph1: MFMA Am0 x Bn23; read Am1(t); stage B0B1(t+1) ---- */      \
        half8 a1[4][2];                                                         \
        _Pragma("unroll")                                                       \
        for (int m = 0; m < 4; ++m) {                                           \
            a1[m][0] = *(const half8*)(smem + (cb) + aB1 + m * 2048 + ck0);     \
            a1[m][1] = *(const half8*)(smem + (cb) + aB1 + m * 2048 + ck1);     \
        }                                                                       \
        if (pref) { STAGE_B(0, nb, colb); STAGE_B(1, nb, colb);                 \
            asm volatile("s_waitcnt vmcnt(2)" ::: "memory"); }                  \
        else asm volatile("s_waitcnt vmcnt(0)" ::: "memory");                   \
        BAR_MFMA(0, AC, b1, 2)                                                  \
        /* ---- ph2: MFMA Am1 x Bn01; read Am0(t+1) m01; stage B2B3(t+1) --- */ \
        if (pref) {                                                             \
            _Pragma("unroll")                                                   \
            for (int m = 0; m < 2; ++m) {                                       \
                AN[m][0] = *(const half8*)(smem + (nb) + aB0 + m * 2048 + ck0); \
                AN[m][1] = *(const half8*)(smem + (nb) + aB0 + m * 2048 + ck1); \
            }                                                                   \
            STAGE_B(2, nb, colb); STAGE_B(3, nb, colb);                         \
            asm volatile("s_waitcnt vmcnt(2)" ::: "memory");                    \
        }                                                                       \
        BAR_MFMA(4, a1, BC, 0)                                                  \
        /* ---- ph3: MFMA Am1 x Bn23; read Am0(t+1) m23 + Bn01(t+1);          */\
        /* ---- stage A2A3(t+1) ----                                          */\
        if (pref) {                                                             \
            _Pragma("unroll")                                                   \
            for (int m = 2; m < 4; ++m) {                                       \
                AN[m][0] = *(const half8*)(smem + (nb) + aB0 + m * 2048 + ck0); \
                AN[m][1] = *(const half8*)(smem + (nb) + aB0 + m * 2048 + ck1); \
            }                                                                   \
            _Pragma("unroll")                                                   \
            for (int n = 0; n < 2; ++n) {                                       \
                BN[n][0] = *(const half8*)(smem + (nb) + bB0 + n * 2048 + ck0); \
                BN[n][1] = *(const half8*)(smem + (nb) + bB0 + n * 2048 + ck1); \
            }                                                                   \
            STAGE_A(2, nb, colb); STAGE_A(3, nb, colb);                         \
            asm volatile("s_waitcnt vmcnt(2)" ::: "memory");                    \
        }                                                                       \
        BAR_MFMA(4, a1, b1, 2)                                                  \
    }

    // ---- prologue: stage tile 0 (buf0) in steady-state slot order ----
    STAGE_A(0, 0, 0); STAGE_A(1, 0, 0);
    STAGE_B(0, 0, 0); STAGE_B(1, 0, 0);
    STAGE_B(2, 0, 0); STAGE_B(3, 0, 0);
    STAGE_A(2, 0, 0); STAGE_A(3, 0, 0);
    asm volatile("s_waitcnt vmcnt(2)" ::: "memory");  // A0A1,B0B1,B2B3 resident
    __builtin_amdgcn_s_barrier();
    // pre-read tile0's Am0 + Bn01 into the "even" register set
#pragma unroll
    for (int m = 0; m < 4; ++m) {
        aE[m][0] = *(const half8*)(smem + aB0 + m * 2048 + ck0);
        aE[m][1] = *(const half8*)(smem + aB0 + m * 2048 + ck1);
    }
#pragma unroll
    for (int n = 0; n < 2; ++n) {
        bE[n][0] = *(const half8*)(smem + bB0 + n * 2048 + ck0);
        bE[n][1] = *(const half8*)(smem + bB0 + n * 2048 + ck1);
    }

    for (int kt = 0; kt < ntiles; kt += 2) {
        TILE(0, 65536, aE, bE, aO, bO, (size_t)(kt + 1) * 128, true)
        TILE(65536, 0, aO, bO, aE, bE, (size_t)(kt + 2) * 128, (kt + 2 < ntiles))
    }

    // epilogue: C/D layout col = lane&15, row = (lane>>4)*4 + reg
    const int cn  = lane & 15;
    const int rm4 = (lane >> 4) * 4;
    float* dst = z ? P : C;
#pragma unroll
    for (int nf = 0; nf < 4; ++nf) {
        int col = bn * 256 + wn * 64 + nf * 16 + cn;
        float bv = z ? 0.0f : bias[col];
#pragma unroll
        for (int mf = 0; mf < 8; ++mf) {
            int row = bm * 256 + wm * 128 + mf * 16 + rm4;
            float* cp = dst + (size_t)row * OUT_F + col;
#pragma unroll
            for (int r = 0; r < 4; ++r)
                cp[(size_t)r * OUT_F] = acc[mf][nf][r] + bv;
        }
    }
}

// ---- split-K reduction: C += P (C already holds partial0 + bias) ----
__global__ __launch_bounds__(256) void reduce_kernel(float* __restrict__ C,
        const float* __restrict__ P) {
    const int n4 = M_ROWS * OUT_F / 4;
    float4* c4 = (float4*)C;
    const float4* p4 = (const float4*)P;
    for (int i = blockIdx.x * 256 + threadIdx.x; i < n4; i += 2048 * 256) {
        float4 a = c4[i];
        float4 b = p4[i];
        a.x += b.x; a.y += b.y; a.z += b.z; a.w += b.w;
        c4[i] = a;
    }
}

extern "C" void kernel_launch(void* const* d_in, const int* in_sizes, int n_in,
                              void* d_out, int out_size, void* d_ws, size_t ws_size,
                              hipStream_t stream) {
    const float* x     = (const float*)d_in[0];
    const float* gamma = (const float*)d_in[1];
    const float* beta  = (const float*)d_in[2];
    const float* sw    = (const float*)d_in[3];
    const float* bw    = (const float*)d_in[4];
    const float* bb    = (const float*)d_in[5];
    float* out = (float*)d_out;

    char* ws = (char*)d_ws;
    size_t offW = 0;
    size_t offA = (size_t)OUT_F * KDIM * 2;                       // 18.9 MB
    size_t offP = offA + (size_t)M_ROWS * KDIM * 2;               // +151 MB
    size_t need = offP + (size_t)M_ROWS * OUT_F * 4;              // +33.5 MB
    _Float16* Wb = (_Float16*)(ws + offW);
    _Float16* Ab = (_Float16*)(ws + offA);
    float*    Pb = (float*)(ws + offP);
    const int split = (ws_size >= need);

    static int s_attr = 0;
    if (!s_attr) {
        hipFuncSetAttribute(reinterpret_cast<const void*>(gemm_kernel),
                            hipFuncAttributeMaxDynamicSharedMemorySize, 131072);
        s_attr = 1;
    }

    prep_kernel<<<A_BLOCKS + W_BLOCKS, 256, 0, stream>>>(
        x, gamma, beta, sw, bw, Ab, Wb);
    if (split) {
        gemm_kernel<<<256, 512, 131072, stream>>>(Ab, Wb, bb, out, Pb, KHALF / 64, 2);
        reduce_kernel<<<2048, 256, 0, stream>>>(out, Pb);
    } else {
        gemm_kernel<<<128, 512, 131072, stream>>>(Ab, Wb, bb, out, Pb, KDIM / 64, 1);
    }
}

// Round 6
// 287.529 us; speedup vs baseline: 3.4407x; 3.4407x over previous
//
#include <hip/hip_runtime.h>
#include <hip/hip_bf16.h>
#include <stdint.h>

#define IN_F 1024
#define OUT_F 1024
#define NG 8
#define KSPLINE 8192            // IN_F * NG
#define KDIM 9216               // KSPLINE + IN_F
#define KHALF 4608              // split-K half (72 tiles of 64)
#define M_ROWS 8192
#define LOG2E 1.4426950408889634f
// KC = 1.75 * sqrt(log2(e)) : basis = exp(-((xn-c)*1.75)^2) = 2^(-(xn*KC - c*KC)^2)
#define KC 2.1019642153762872f

#define A_BLOCKS (M_ROWS / 4)           // 2048 (4 rows per block, wave-per-row)
#define W_BLOCKS ((OUT_F * 2304) / 256) // 9216
#define RB (KDIM * 2)                   // A/W row bytes (18432)

using half4v = __attribute__((ext_vector_type(4))) _Float16;
using half8  = __attribute__((ext_vector_type(8))) _Float16;
using f32x4  = __attribute__((ext_vector_type(4))) float;

#define AS1 __attribute__((address_space(1)))
#define AS3 __attribute__((address_space(3)))

// ---- merged prep: blocks [0, A_BLOCKS) build A; [A_BLOCKS, +W_BLOCKS) build W
// R6: nontemporal stores for A (gemm fetches A from HBM anyway — FETCH=147MB
// proves no cache reuse) and nontemporal loads for read-once x/sw/bw.
// (R5 compile fix: nontemporal builtins need ext-vector types, not
// HIP_vector_type float4 — use f32x4.)
__global__ __launch_bounds__(256) void prep_kernel(
        const float* __restrict__ x, const float* __restrict__ gamma,
        const float* __restrict__ beta, const float* __restrict__ sw,
        const float* __restrict__ bw, _Float16* __restrict__ A,
        _Float16* __restrict__ W) {
    if (blockIdx.x >= A_BLOCKS) {
        int idx = (blockIdx.x - A_BLOCKS) * 256 + threadIdx.x;  // one float4 each
        int o   = idx / 2304;
        int k4  = idx - o * 2304;
        f32x4 v;
        if (k4 < 2048) v = __builtin_nontemporal_load(&((const f32x4*)sw)[(size_t)o * 2048 + k4]);
        else           v = __builtin_nontemporal_load(&((const f32x4*)bw)[(size_t)o * 256 + (k4 - 2048)]);
        half4v h = { (_Float16)v.x, (_Float16)v.y, (_Float16)v.z, (_Float16)v.w };
        *(half4v*)(W + (size_t)idx * 4) = h;   // W stays cached (re-read 8x in gemm)
        return;
    }
    const int wave = threadIdx.x >> 6, lane = threadIdx.x & 63;
    const int row = blockIdx.x * 4 + wave;
    const float* xr = x + (size_t)row * IN_F;

    float xv[16];
    float s = 0.0f, s2 = 0.0f;
#pragma unroll
    for (int j = 0; j < 16; ++j) {
        float v = __builtin_nontemporal_load(&xr[j * 64 + lane]);
        xv[j] = v;
        s += v;
        s2 += v * v;
    }
#pragma unroll
    for (int off = 32; off > 0; off >>= 1) {
        s  += __shfl_xor(s, off);
        s2 += __shfl_xor(s2, off);
    }
    float mu   = s * (1.0f / IN_F);
    float var  = s2 * (1.0f / IN_F) - mu * mu;
    float rstd = rsqrtf(var + 1e-5f);

    const float cq[8] = {
        -2.0000000f * KC, -1.4285715f * KC, -0.8571429f * KC, -0.2857143f * KC,
         0.2857143f * KC,  0.8571429f * KC,  1.4285715f * KC,  2.0000000f * KC };

    _Float16* Arow = A + (size_t)row * KDIM;
    half8* basis_out = (half8*)Arow;                       // chunk f = feature f
    _Float16* silu_out = Arow + KSPLINE;
#pragma unroll
    for (int j = 0; j < 16; ++j) {
        int f = j * 64 + lane;
        float xs = xv[j];
        float xq = ((xs - mu) * rstd * gamma[f] + beta[f]) * KC;
        half8 h;
#pragma unroll
        for (int g = 0; g < 8; ++g) {
            float v = xq - cq[g];
            h[g] = (_Float16)exp2f(-(v * v));
        }
        __builtin_nontemporal_store(h, &basis_out[f]);
        __builtin_nontemporal_store((_Float16)(xs / (1.0f + exp2f(-xs * LOG2E))), &silu_out[f]);
    }
}

// ---------------- GEMM (R3-verified version: 148us, MfmaUtil 45%,
// VGPR 116, 0 conflicts): 256x256 tile, 8 waves (2Mx4N, per-wave 128x64),
// BK=64, double-buffered 128KB LDS, split-K=2. 4-phase quadrant schedule;
// each phase: {ds_read 0/4/12 frags; counted vmcnt(2); stage 2 slots of t+1;
// barrier; lgkmcnt(0); setprio(1); 16 MFMA; setprio(0); barrier}. Staging
// slots consumed in issue order, >=2 phases old at wait; vmcnt never 0
// mid-loop. XOR swizzle (row&7)<<4 applied both-sides.
__global__ __launch_bounds__(512, 2) void gemm_kernel(
        const _Float16* __restrict__ A, const _Float16* __restrict__ W,
        const float* __restrict__ bias, float* __restrict__ C,
        float* __restrict__ P, int ntiles, int gpz) {
    extern __shared__ __align__(16) char smem[];   // 2 x [A 32K | B 32K]
    const int tid  = threadIdx.x;
    const int wave = tid >> 6, lane = tid & 63;
    const int wm = wave >> 2, wn = wave & 3;       // 2M x 4N wave grid

    // bijective XCD swizzle (grid % 8 == 0): 4 bn-siblings per group
    const int lb = blockIdx.x;
    const int per_xcd = gridDim.x >> 5;
    const int xcd = lb & 7, sl = lb >> 3;
    const int g  = xcd * per_xcd + (sl >> 2);
    const int bn = sl & 3;
    const int bm = g / gpz;
    const int z  = g - bm * gpz;

    // ---- staging sources: slot s covers 64 rows (8 per wave), lane chunk
    // pre-swizzled so linear LDS dest yields swizzled layout
    const int l8 = lane >> 3;
    const int chunkswz = ((lane & 7) ^ l8) << 4;
    const size_t zoff = (size_t)z * (KHALF * 2);
    // A slot->rowbase {0,128,64,192}: slots {0,1}=mh0 rows, {2,3}=mh1 rows
    // B slot->rowbase {0,128,32,160}: slots {0,1}=nh0 rows, {2,3}=nh1 rows
    const int gA[4] = {0, 128, 64, 192};
    const int gB[4] = {0, 128, 32, 160};
    const char* pA[4];
    const char* pB[4];
#pragma unroll
    for (int s = 0; s < 4; ++s) {
        pA[s] = (const char*)A + (size_t)(bm * 256 + gA[s] + wave * 8 + l8) * RB
                + zoff + chunkswz;
        pB[s] = (const char*)W + (size_t)(bn * 256 + gB[s] + (wave >> 2) * 64
                + (wave & 3) * 8 + l8) * RB + zoff + chunkswz;
    }

#define STAGE_A(s, nb, colb) __builtin_amdgcn_global_load_lds( \
        (const AS1 void*)(pA[s] + (colb)), \
        (AS3 void*)(smem + (nb) + (s) * 8192 + wave * 1024), 16, 0, 0)
#define STAGE_B(s, nb, colb) __builtin_amdgcn_global_load_lds( \
        (const AS1 void*)(pB[s] + (colb)), \
        (AS3 void*)(smem + (nb) + 32768 + (s) * 8192 + wave * 1024), 16, 0, 0)

    // ---- ds_read offsets (swizzled) ----
    const int lm  = lane & 15;
    const int hi  = (lane >> 4) << 4;
    const int swz = (lm & 7) << 4;
    const int ck0 = (0  + hi) ^ swz;               // kh0 chunk byte
    const int ck1 = (64 + hi) ^ swz;               // kh1
    const int aB0 = (0 + wm) * 8192 + lm * 128;    // mh0 slots; frag mf -> +mf*2048
    const int aB1 = (2 + wm) * 8192 + lm * 128;    // mh1 slots
    const int bB0 = 32768 + (0 + (wn >> 1)) * 8192 + ((wn & 1) * 32 + lm) * 128;
    const int bB1 = 32768 + (2 + (wn >> 1)) * 8192 + ((wn & 1) * 32 + lm) * 128;

    f32x4 acc[8][4] = {};

    // ---- prologue: tile 0 into buf0, steady-state issue order ----
    STAGE_A(0, 0, 0); STAGE_A(1, 0, 0);
    STAGE_B(0, 0, 0); STAGE_B(1, 0, 0);
    STAGE_B(2, 0, 0); STAGE_B(3, 0, 0);
    STAGE_A(2, 0, 0); STAGE_A(3, 0, 0);
    asm volatile("s_waitcnt vmcnt(4)" ::: "memory");   // A0A1,B0B1 resident
    __builtin_amdgcn_s_barrier();

    for (int kt = 0; kt < ntiles; ++kt) {
        const int cb = (kt & 1) * 65536;
        const int nb = cb ^ 65536;
        const size_t col = (size_t)(kt + 1) * 128;
        const bool pref = (kt + 1 < ntiles);

        // ===== phase 0: mf0-3 x nf0-1 (reads A0A1+B0B1; stage A0A1(t+1)) =====
        half8 aF[4][2], bF[2][2];
#pragma unroll
        for (int m = 0; m < 4; ++m) {
            aF[m][0] = *(const half8*)(smem + cb + aB0 + m * 2048 + ck0);
            aF[m][1] = *(const half8*)(smem + cb + aB0 + m * 2048 + ck1);
        }
#pragma unroll
        for (int n = 0; n < 2; ++n) {
            bF[n][0] = *(const half8*)(smem + cb + bB0 + n * 2048 + ck0);
            bF[n][1] = *(const half8*)(smem + cb + bB0 + n * 2048 + ck1);
        }
        asm volatile("s_waitcnt vmcnt(2)" ::: "memory");   // B2B3(t) resident
        if (pref) { STAGE_A(0, nb, col); STAGE_A(1, nb, col); }
        asm volatile("s_waitcnt lgkmcnt(8)" ::: "memory"); // throttle (12 reads)
        __builtin_amdgcn_s_barrier();
        asm volatile("s_waitcnt lgkmcnt(0)" ::: "memory");
        __builtin_amdgcn_s_setprio(1);
#pragma unroll
        for (int n = 0; n < 2; ++n)
#pragma unroll
            for (int m = 0; m < 4; ++m)
                acc[m][n] = __builtin_amdgcn_mfma_f32_16x16x32_f16(aF[m][0], bF[n][0], acc[m][n], 0, 0, 0);
#pragma unroll
        for (int n = 0; n < 2; ++n)
#pragma unroll
            for (int m = 0; m < 4; ++m)
                acc[m][n] = __builtin_amdgcn_mfma_f32_16x16x32_f16(aF[m][1], bF[n][1], acc[m][n], 0, 0, 0);
        __builtin_amdgcn_s_setprio(0);
        __builtin_amdgcn_s_barrier();

        // ===== phase 1: mf0-3 x nf2-3 (reads B2B3; stage B0B1(t+1)) =====
        half8 bG[2][2];
#pragma unroll
        for (int n = 0; n < 2; ++n) {
            bG[n][0] = *(const half8*)(smem + cb + bB1 + n * 2048 + ck0);
            bG[n][1] = *(const half8*)(smem + cb + bB1 + n * 2048 + ck1);
        }
        if (pref) {
            asm volatile("s_waitcnt vmcnt(2)" ::: "memory");  // A2A3(t) resident
            STAGE_B(0, nb, col); STAGE_B(1, nb, col);
        } else {
            asm volatile("s_waitcnt vmcnt(0)" ::: "memory");
        }
        __builtin_amdgcn_s_barrier();
        asm volatile("s_waitcnt lgkmcnt(0)" ::: "memory");
        __builtin_amdgcn_s_setprio(1);
#pragma unroll
        for (int n = 0; n < 2; ++n)
#pragma unroll
            for (int m = 0; m < 4; ++m)
                acc[m][2 + n] = __builtin_amdgcn_mfma_f32_16x16x32_f16(aF[m][0], bG[n][0], acc[m][2 + n], 0, 0, 0);
#pragma unroll
        for (int n = 0; n < 2; ++n)
#pragma unroll
            for (int m = 0; m < 4; ++m)
                acc[m][2 + n] = __builtin_amdgcn_mfma_f32_16x16x32_f16(aF[m][1], bG[n][1], acc[m][2 + n], 0, 0, 0);
        __builtin_amdgcn_s_setprio(0);
        __builtin_amdgcn_s_barrier();

        // ===== phase 2: mf4-7 x nf0-1 (reads A2A3; stage B2B3(t+1)) =====
        half8 aG[4][2];
#pragma unroll
        for (int m = 0; m < 4; ++m) {
            aG[m][0] = *(const half8*)(smem + cb + aB1 + m * 2048 + ck0);
            aG[m][1] = *(const half8*)(smem + cb + aB1 + m * 2048 + ck1);
        }
        if (pref) { STAGE_B(2, nb, col); STAGE_B(3, nb, col); }
        __builtin_amdgcn_s_barrier();
        asm volatile("s_waitcnt lgkmcnt(0)" ::: "memory");
        __builtin_amdgcn_s_setprio(1);
#pragma unroll
        for (int n = 0; n < 2; ++n)
#pragma unroll
            for (int m = 0; m < 4; ++m)
                acc[4 + m][n] = __builtin_amdgcn_mfma_f32_16x16x32_f16(aG[m][0], bF[n][0], acc[4 + m][n], 0, 0, 0);
#pragma unroll
        for (int n = 0; n < 2; ++n)
#pragma unroll
            for (int m = 0; m < 4; ++m)
                acc[4 + m][n] = __builtin_amdgcn_mfma_f32_16x16x32_f16(aG[m][1], bF[n][1], acc[4 + m][n], 0, 0, 0);
        __builtin_amdgcn_s_setprio(0);
        __builtin_amdgcn_s_barrier();

        // ===== phase 3: mf4-7 x nf2-3 (no reads; stage A2A3(t+1)) =====
        if (pref) {
            asm volatile("s_waitcnt vmcnt(2)" ::: "memory");  // A0A1,B0B1(t+1) resident
            STAGE_A(2, nb, col); STAGE_A(3, nb, col);
        }
        __builtin_amdgcn_s_barrier();
        __builtin_amdgcn_s_setprio(1);
#pragma unroll
        for (int n = 0; n < 2; ++n)
#pragma unroll
            for (int m = 0; m < 4; ++m)
                acc[4 + m][2 + n] = __builtin_amdgcn_mfma_f32_16x16x32_f16(aG[m][0], bG[n][0], acc[4 + m][2 + n], 0, 0, 0);
#pragma unroll
        for (int n = 0; n < 2; ++n)
#pragma unroll
            for (int m = 0; m < 4; ++m)
                acc[4 + m][2 + n] = __builtin_amdgcn_mfma_f32_16x16x32_f16(aG[m][1], bG[n][1], acc[4 + m][2 + n], 0, 0, 0);
        __builtin_amdgcn_s_setprio(0);
        __builtin_amdgcn_s_barrier();
    }

    // epilogue: C/D layout col = lane&15, row = (lane>>4)*4 + reg
    const int cn  = lane & 15;
    const int rm4 = (lane >> 4) * 4;
    float* dst = z ? P : C;
#pragma unroll
    for (int nf = 0; nf < 4; ++nf) {
        int col = bn * 256 + wn * 64 + nf * 16 + cn;
        float bv = z ? 0.0f : bias[col];
#pragma unroll
        for (int mf = 0; mf < 8; ++mf) {
            int row = bm * 256 + wm * 128 + mf * 16 + rm4;
            float* cp = dst + (size_t)row * OUT_F + col;
#pragma unroll
            for (int r = 0; r < 4; ++r)
                cp[(size_t)r * OUT_F] = acc[mf][nf][r] + bv;
        }
    }
}

// ---- split-K reduction: C += P (C already holds partial0 + bias) ----
__global__ __launch_bounds__(256) void reduce_kernel(float* __restrict__ C,
        const float* __restrict__ P) {
    const int n4 = M_ROWS * OUT_F / 4;
    float4* c4 = (float4*)C;
    const float4* p4 = (const float4*)P;
    for (int i = blockIdx.x * 256 + threadIdx.x; i < n4; i += 2048 * 256) {
        float4 a = c4[i];
        float4 b = p4[i];
        a.x += b.x; a.y += b.y; a.z += b.z; a.w += b.w;
        c4[i] = a;
    }
}

extern "C" void kernel_launch(void* const* d_in, const int* in_sizes, int n_in,
                              void* d_out, int out_size, void* d_ws, size_t ws_size,
                              hipStream_t stream) {
    const float* x     = (const float*)d_in[0];
    const float* gamma = (const float*)d_in[1];
    const float* beta  = (const float*)d_in[2];
    const float* sw    = (const float*)d_in[3];
    const float* bw    = (const float*)d_in[4];
    const float* bb    = (const float*)d_in[5];
    float* out = (float*)d_out;

    char* ws = (char*)d_ws;
    size_t offW = 0;
    size_t offA = (size_t)OUT_F * KDIM * 2;                       // 18.9 MB
    size_t offP = offA + (size_t)M_ROWS * KDIM * 2;               // +151 MB
    size_t need = offP + (size_t)M_ROWS * OUT_F * 4;              // +33.5 MB
    _Float16* Wb = (_Float16*)(ws + offW);
    _Float16* Ab = (_Float16*)(ws + offA);
    float*    Pb = (float*)(ws + offP);
    const int split = (ws_size >= need);

    static int s_attr = 0;
    if (!s_attr) {
        (void)hipFuncSetAttribute(reinterpret_cast<const void*>(gemm_kernel),
                            hipFuncAttributeMaxDynamicSharedMemorySize, 131072);
        s_attr = 1;
    }

    prep_kernel<<<A_BLOCKS + W_BLOCKS, 256, 0, stream>>>(
        x, gamma, beta, sw, bw, Ab, Wb);
    if (split) {
        gemm_kernel<<<256, 512, 131072, stream>>>(Ab, Wb, bb, out, Pb, KHALF / 64, 2);
        reduce_kernel<<<2048, 256, 0, stream>>>(out, Pb);
    } else {
        gemm_kernel<<<128, 512, 131072, stream>>>(Ab, Wb, bb, out, Pb, KDIM / 64, 1);
    }
}